// Round 6
// baseline (1078.031 us; speedup 1.0000x reference)
//
#include <hip/hip_runtime.h>
#include <cmath>

// ---------------------------------------------------------------------------
// TimestepVisionTransformer — fp32. Round 5: both-parity conv threads
// (thread computes 2x2 output quad: 9 loads -> 16G FMAs per ci).
// B=128, IMG=224, P=16, C_IN=1, E=96, H=4, d=24, NAX=14, N=196, M=B*N=25088
// ---------------------------------------------------------------------------

#define B_   128
#define NPATCH 196
#define M_ROWS (B_*NPATCH)     // 25088
#define E_   96
#define KS   4
#define SEG  49

// ---------------------------------------------------------------------------
// time embedding: 1 block x 128 threads
// ---------------------------------------------------------------------------
__global__ void k_time(const float* __restrict__ ts,
                       const float* __restrict__ Wt1, const float* __restrict__ bt1,
                       const float* __restrict__ Wt2, const float* __restrict__ bt2,
                       float* __restrict__ timev)
{
    __shared__ float h[128];
    float e = 0.69314718055994530942f * ts[0];
    float sv = sinf(e), cv = cosf(e);
    int t = threadIdx.x;
    float z = sv * Wt1[t] + cv * Wt1[128 + t] + bt1[t];
    h[t] = z / (1.f + expf(-z));
    __syncthreads();
    if (t < 96) {
        float acc = bt2[t];
        for (int j = 0; j < 128; ++j) acc += h[j] * Wt2[j * 96 + t];
        timev[t] = acc;
    }
}

// ---------------------------------------------------------------------------
// weight repack for all 4 convT layers into per-parity float4 taps.
// Wr[par][ci][o][4]; layer offsets (floats): L1=0, L2=73728, L3=92160, L4=96768
// ---------------------------------------------------------------------------
__global__ void __launch_bounds__(256) k_repack(const float* __restrict__ w1,
                                                const float* __restrict__ w2,
                                                const float* __restrict__ w3,
                                                const float* __restrict__ w4f,
                                                float* __restrict__ wr)
{
    int i = blockIdx.x * 256 + threadIdx.x;
    const float* src; int CIN, COUT, e; float* dst;
    if      (i < 73728) { src = w1;  CIN = 96; COUT = 48; e = i;          dst = wr; }
    else if (i < 92160) { src = w2;  CIN = 48; COUT = 24; e = i - 73728;  dst = wr + 73728; }
    else if (i < 96768) { src = w3;  CIN = 24; COUT = 12; e = i - 92160;  dst = wr + 92160; }
    else if (i < 96960) { src = w4f; CIN = 12; COUT = 1;  e = i - 96768;  dst = wr + 96768; }
    else return;
    int per = CIN * COUT * 4;
    int par = e / per, rem = e % per;
    int ci = rem / (COUT * 4);
    int o  = (rem >> 2) % COUT;
    int j  = rem & 3;
    int ry = par >> 1, rx = par & 1;
    int wy = (j < 2)  ? (3 - ry) : (1 - ry);
    int wx = (j & 1)  ? (1 - rx) : (3 - rx);
    dst[e] = src[(ci * COUT + o) * 16 + wy * 4 + wx];
}

// ---------------------------------------------------------------------------
// zero the borders of XP1 [128*96 planes][16][16] (interior written by MLP3)
// ---------------------------------------------------------------------------
__global__ void __launch_bounds__(256) k_zb(float* __restrict__ xp)
{
    int idx = blockIdx.x * 256 + threadIdx.x;   // plane*64 + j
    int plane = idx >> 6, j = idx & 63;
    if (plane >= 12288 || j >= 60) return;
    int py, px;
    if      (j < 16) { py = 0;      px = j; }
    else if (j < 32) { py = 15;     px = j - 16; }
    else if (j < 46) { py = j - 31; px = 0; }
    else             { py = j - 45; px = 15; }
    xp[(size_t)plane * 256 + py * 16 + px] = 0.f;
}

// ---------------------------------------------------------------------------
// patch embed GEMM  [25088 x 256] @ WpT[256 x 96]  + bias + RoPE epilogue
// ---------------------------------------------------------------------------
__global__ void __launch_bounds__(256) k_patch(const float* __restrict__ x,
                                               const float* __restrict__ Wp,
                                               const float* __restrict__ bp,
                                               float* __restrict__ out)
{
    __shared__ float As[64][65];
    __shared__ float Ws[64][97];
    int t = threadIdx.x;
    int p0 = blockIdx.x * 64;
    int rg = t >> 4, cg = t & 15;
    float acc[4][6] = {};

    for (int kc = 0; kc < 4; ++kc) {
        __syncthreads();
        for (int idx = t; idx < 64 * 64; idx += 256) {
            int p = idx >> 6, kl = idx & 63;
            int patch = p0 + p;
            int b = patch / NPATCH, n = patch % NPATCH;
            int ny = n / 14, nx = n % 14;
            int py = kc * 4 + (kl >> 4), px = kl & 15;
            As[p][kl] = x[((size_t)b * 224 + ny * 16 + py) * 224 + nx * 16 + px];
        }
        for (int idx = t; idx < 64 * 96; idx += 256) {
            int e = idx >> 6, kl = idx & 63;
            Ws[kl][e] = Wp[e * 256 + kc * 64 + kl];
        }
        __syncthreads();
        for (int kk = 0; kk < 64; ++kk) {
            float a0 = As[rg * 4 + 0][kk];
            float a1 = As[rg * 4 + 1][kk];
            float a2 = As[rg * 4 + 2][kk];
            float a3 = As[rg * 4 + 3][kk];
            const float* wrow = &Ws[kk][cg * 6];
            #pragma unroll
            for (int j = 0; j < 6; ++j) {
                float wv = wrow[j];
                acc[0][j] += a0 * wv; acc[1][j] += a1 * wv;
                acc[2][j] += a2 * wv; acc[3][j] += a3 * wv;
            }
        }
    }
    #pragma unroll
    for (int i = 0; i < 4; ++i) {
        int patch = p0 + rg * 4 + i;
        int n = patch % NPATCH;
        int ny = n / 14, nx = n % 14;
        float yx = (float)(ny + nx);
        #pragma unroll
        for (int j = 0; j < 3; ++j) {
            int e0 = cg * 6 + 2 * j;
            float xe = acc[i][2 * j]     + bp[e0];
            float ye = acc[i][2 * j + 1] + bp[e0 + 1];
            float fi = (float)(e0 >> 1);
            float theta = expf(fi * (-2.f / 96.f) * 9.210340371976184f);
            float ang = theta * yx;
            float c = cosf(ang), s = sinf(ang);
            out[(size_t)patch * 96 + e0]     = xe * c - ye * s;
            out[(size_t)patch * 96 + e0 + 1] = xe * s + ye * c;
        }
    }
}

// ---------------------------------------------------------------------------
// row LayerNorm over 96, wave per row
// ---------------------------------------------------------------------------
__global__ void __launch_bounds__(256) k_ln_row(const float* __restrict__ x,
                                                const float* __restrict__ g,
                                                const float* __restrict__ bv,
                                                float* __restrict__ out, int M)
{
    int lane = threadIdx.x & 63;
    int gw = (blockIdx.x * 256 + threadIdx.x) >> 6;
    int nw = (gridDim.x * 256) >> 6;
    float g0 = g[lane], b0 = bv[lane];
    float g1 = 0.f, b1 = 0.f;
    if (lane < 32) { g1 = g[64 + lane]; b1 = bv[64 + lane]; }
    for (int r = gw; r < M; r += nw) {
        const float* xr = x + (size_t)r * 96;
        float a = xr[lane];
        float c = (lane < 32) ? xr[64 + lane] : 0.f;
        float s = a + c, q = a * a + c * c;
        #pragma unroll
        for (int off = 32; off; off >>= 1) {
            s += __shfl_xor(s, off);
            q += __shfl_xor(q, off);
        }
        float mu = s * (1.f / 96.f);
        float rstd = rsqrtf(q * (1.f / 96.f) - mu * mu + 1e-5f);
        float* orow = out + (size_t)r * 96;
        orow[lane] = (a - mu) * rstd * g0 + b0;
        if (lane < 32) orow[64 + lane] = (c - mu) * rstd * g1 + b1;
    }
}

// ---------------------------------------------------------------------------
// generic row GEMM: A[M,96] @ W[96, NCHUNKS*96] + bias, epilogues
// PADW: write into padded conv-input layout XP1[b][col][16][16] interior
// ---------------------------------------------------------------------------
template<int NCHUNKS, bool SILU, bool RES, bool ADDTIME, bool PADW>
__global__ void __launch_bounds__(256) k_gemm96(const float* __restrict__ A,
                                                const float* __restrict__ W,
                                                const float* __restrict__ bias,
                                                const float* __restrict__ res,
                                                const float* __restrict__ timev,
                                                float* __restrict__ out)
{
    __shared__ float As[64][97];
    __shared__ float Ws[96 * 96];
    constexpr int NTOT = NCHUNKS * 96;
    int t = threadIdx.x;
    size_t row0 = (size_t)blockIdx.x * 64;
    for (int idx = t; idx < 64 * 96; idx += 256)
        As[idx / 96][idx % 96] = A[row0 * 96 + idx];
    int rg = t >> 4, cg = t & 15;
    for (int ch = 0; ch < NCHUNKS; ++ch) {
        __syncthreads();
        for (int idx = t; idx < 96 * 96; idx += 256) {
            int k = idx / 96, c = idx % 96;
            Ws[idx] = W[k * NTOT + ch * 96 + c];
        }
        __syncthreads();
        float acc[4][6] = {};
        for (int kk = 0; kk < 96; ++kk) {
            float a0 = As[rg * 4 + 0][kk];
            float a1 = As[rg * 4 + 1][kk];
            float a2 = As[rg * 4 + 2][kk];
            float a3 = As[rg * 4 + 3][kk];
            const float* wrow = &Ws[kk * 96 + cg * 6];
            #pragma unroll
            for (int j = 0; j < 6; ++j) {
                float wv = wrow[j];
                acc[0][j] += a0 * wv; acc[1][j] += a1 * wv;
                acc[2][j] += a2 * wv; acc[3][j] += a3 * wv;
            }
        }
        #pragma unroll
        for (int i = 0; i < 4; ++i) {
            size_t row = row0 + rg * 4 + i;
            #pragma unroll
            for (int j = 0; j < 6; ++j) {
                int lc = cg * 6 + j;
                int col = ch * 96 + lc;
                float v = acc[i][j] + bias[col];
                if constexpr (RES)     v += res[row * 96 + lc];
                if constexpr (ADDTIME) v += timev[lc];
                if constexpr (SILU)    v = v / (1.f + expf(-v));
                if constexpr (PADW) {
                    size_t b = row / NPATCH; int n = (int)(row % NPATCH);
                    int ny = n / 14, nx = n % 14;
                    out[(b * 96 + col) * 256 + (1 + ny) * 16 + (1 + nx)] = v;
                } else {
                    out[row * NTOT + col] = v;
                }
            }
        }
    }
}

// ---------------------------------------------------------------------------
// attention partials: block = (b,h,seg). Stage 49 K/V rows in LDS; one
// thread = one query; uniform-address ds_read -> broadcast.
// ---------------------------------------------------------------------------
__global__ void __launch_bounds__(256) k_attn_part(const float* __restrict__ qkv,
                                                   float* __restrict__ part)
{
    int blk = blockIdx.x;          // bh*KS + seg
    int seg = blk % KS;
    int bh  = blk / KS;
    int b = bh >> 2, h = bh & 3;
    const float* base = qkv + (size_t)b * NPATCH * 288 + h * 24;
    __shared__ __align__(16) float KV[SEG * 48];
    int t = threadIdx.x;
    int k0 = seg * SEG;
    for (int i = t; i < SEG * 48; i += 256) {
        int k = i / 48, j = i % 48;
        KV[i] = base[(size_t)(k0 + k) * 288 + 96 + (j < 24 ? j : j + 72)];
    }
    __syncthreads();

    int q = (t < NPATCH) ? t : 0;
    float qv[24], acc[24];
    const float4* qrow = (const float4*)(base + (size_t)q * 288);
    #pragma unroll
    for (int j = 0; j < 6; ++j) {
        float4 v = qrow[j];
        qv[4 * j] = v.x; qv[4 * j + 1] = v.y; qv[4 * j + 2] = v.z; qv[4 * j + 3] = v.w;
    }
    #pragma unroll
    for (int d = 0; d < 24; ++d) acc[d] = 0.f;
    float sum = 0.f;
    const float scale = 0.2041241452319315f;   // 1/sqrt(24)

    #pragma unroll 2
    for (int k = 0; k < SEG; ++k) {
        const float4* kr = (const float4*)(&KV[k * 48]);   // uniform addr
        float s0 = 0.f, s1 = 0.f, s2 = 0.f, s3 = 0.f;
        #pragma unroll
        for (int j = 0; j < 6; ++j) {
            float4 Kv = kr[j];
            s0 += qv[4 * j]     * Kv.x;
            s1 += qv[4 * j + 1] * Kv.y;
            s2 += qv[4 * j + 2] * Kv.z;
            s3 += qv[4 * j + 3] * Kv.w;
        }
        float s = (s0 + s1) + (s2 + s3);
        float p = __expf(fminf(s * scale, 60.f));
        sum += p;
        #pragma unroll
        for (int j = 0; j < 6; ++j) {
            float4 Vv = kr[6 + j];
            acc[4 * j]     += p * Vv.x;
            acc[4 * j + 1] += p * Vv.y;
            acc[4 * j + 2] += p * Vv.z;
            acc[4 * j + 3] += p * Vv.w;
        }
    }

    if (t < NPATCH) {
        float4* pp = (float4*)(part + ((size_t)blk * NPATCH + t) * 28);
        #pragma unroll
        for (int j = 0; j < 6; ++j) {
            float4 v;
            v.x = acc[4 * j]; v.y = acc[4 * j + 1];
            v.z = acc[4 * j + 2]; v.w = acc[4 * j + 3];
            pp[j] = v;
        }
        float4 sv; sv.x = sum; sv.y = 0.f; sv.z = 0.f; sv.w = 0.f;
        pp[6] = sv;
    }
}

// ---------------------------------------------------------------------------
// combine K-split partials: o[b][q][h*24..] = Σacc / Σsum
// ---------------------------------------------------------------------------
__global__ void __launch_bounds__(256) k_attn_comb(const float* __restrict__ part,
                                                   float* __restrict__ o)
{
    int idx = blockIdx.x * 256 + threadIdx.x;   // bh*196 + q
    int bh = idx / NPATCH, q = idx % NPATCH;
    int b = bh >> 2, h = bh & 3;
    float acc[24];
    #pragma unroll
    for (int d = 0; d < 24; ++d) acc[d] = 0.f;
    float sum = 0.f;
    #pragma unroll
    for (int s = 0; s < KS; ++s) {
        const float4* pp = (const float4*)(part + ((size_t)(bh * KS + s) * NPATCH + q) * 28);
        #pragma unroll
        for (int j = 0; j < 6; ++j) {
            float4 v = pp[j];
            acc[4 * j]     += v.x;
            acc[4 * j + 1] += v.y;
            acc[4 * j + 2] += v.z;
            acc[4 * j + 3] += v.w;
        }
        sum += pp[6].x;
    }
    float inv = 1.f / sum;
    float4* orow = (float4*)(o + ((size_t)b * NPATCH + q) * 96 + h * 24);
    #pragma unroll
    for (int j = 0; j < 6; ++j) {
        float4 v;
        v.x = acc[4 * j] * inv; v.y = acc[4 * j + 1] * inv;
        v.z = acc[4 * j + 2] * inv; v.w = acc[4 * j + 3] * inv;
        orow[j] = v;
    }
}

// ---------------------------------------------------------------------------
// transposed conv on zero-padded input XP[b][CIN][HIN+2][HIN+2].
// Both-parity threads: one thread = (og, b, input pixel), computing the
// full 2x2 output quad (rows 2py..2py+1, cols 2px..2px+1) for G channels.
// 9 loads -> 16G FMAs per ci. Weights par-major via s_load broadcast.
// grid = (COUT/G) * B*HIN*HIN/256.
// ---------------------------------------------------------------------------
template<int CIN, int HIN, int COUT, int G>
__global__ void __launch_bounds__(256) k_convh(const float* __restrict__ xp,
                                               const float* __restrict__ wr,
                                               const float* __restrict__ bias,
                                               float* __restrict__ out)
{
    constexpr int HP = HIN + 2;
    constexpr int HO = 2 * HIN;
    constexpr int NPB = (B_ * HIN * HIN) / 256;
    int pb = blockIdx.x % NPB;
    int og = blockIdx.x / NPB;
    int o0 = og * G;
    int rem = pb * 256 + threadIdx.x;
    int b   = rem / (HIN * HIN);
    int pix = rem % (HIN * HIN);
    int py = pix / HIN, px = pix % HIN;
    const float* xb = xp + ((size_t)b * CIN) * (HP * HP) + py * HP + px;
    const float4* w4 = (const float4*)wr;
    float a00[G], a01[G], a10[G], a11[G];
    #pragma unroll
    for (int o = 0; o < G; ++o) { a00[o] = 0.f; a01[o] = 0.f; a10[o] = 0.f; a11[o] = 0.f; }
    float r00 = xb[0],          r01 = xb[1],          r02 = xb[2];
    float r10 = xb[HP],         r11 = xb[HP + 1],     r12 = xb[HP + 2];
    float r20 = xb[2 * HP],     r21 = xb[2 * HP + 1], r22 = xb[2 * HP + 2];
    for (int ci = 0; ci < CIN; ++ci) {
        int cn = (ci + 1 < CIN) ? (ci + 1) : (CIN - 1);
        const float* xn = xb + (size_t)cn * (HP * HP);
        float n00 = xn[0],      n01 = xn[1],          n02 = xn[2];
        float n10 = xn[HP],     n11 = xn[HP + 1],     n12 = xn[HP + 2];
        float n20 = xn[2 * HP], n21 = xn[2 * HP + 1], n22 = xn[2 * HP + 2];
        const float4* wp = w4 + (size_t)ci * COUT + o0;
        #pragma unroll
        for (int o = 0; o < G; ++o) {
            float4 W0 = wp[o];
            float4 W1 = wp[o + (size_t)CIN * COUT];
            float4 W2 = wp[o + (size_t)2 * CIN * COUT];
            float4 W3 = wp[o + (size_t)3 * CIN * COUT];
            a00[o] += r00 * W0.x + r01 * W0.y + r10 * W0.z + r11 * W0.w;
            a01[o] += r01 * W1.x + r02 * W1.y + r11 * W1.z + r12 * W1.w;
            a10[o] += r10 * W2.x + r11 * W2.y + r20 * W2.z + r21 * W2.w;
            a11[o] += r11 * W3.x + r12 * W3.y + r21 * W3.z + r22 * W3.w;
        }
        r00 = n00; r01 = n01; r02 = n02;
        r10 = n10; r11 = n11; r12 = n12;
        r20 = n20; r21 = n21; r22 = n22;
    }
    #pragma unroll
    for (int o = 0; o < G; ++o) {
        float bb = bias[o0 + o];
        float* orow = out + ((size_t)(b * COUT + o0 + o) * HO + 2 * py) * HO + 2 * px;
        float2 v0; v0.x = a00[o] + bb; v0.y = a01[o] + bb;
        float2 v1; v1.x = a10[o] + bb; v1.y = a11[o] + bb;
        *(float2*)orow = v0;
        *(float2*)(orow + HO) = v1;
    }
}

// ---------------------------------------------------------------------------
// spatial LN (per b,o over H*H) + per-position affine + silu, writing into
// zero-padded layout XP[plane][(H+2)][(H+2)] for the next conv.
// ---------------------------------------------------------------------------
template<int H>
__global__ void __launch_bounds__(256) k_ln_pad(const float* __restrict__ cin,
                                                const float* __restrict__ g,
                                                const float* __restrict__ bv,
                                                float* __restrict__ xp)
{
    constexpr int HW = H * H;
    constexpr int HP = H + 2;
    constexpr int HWP = HP * HP;
    size_t plane = blockIdx.x;
    const float* src = cin + plane * HW;
    float* dst = xp + plane * HWP;
    int t = threadIdx.x;
    float s = 0.f, q = 0.f;
    for (int i = t; i < HW; i += 256) {
        float v = src[i];
        s += v; q += v * v;
    }
    #pragma unroll
    for (int off = 32; off; off >>= 1) {
        s += __shfl_xor(s, off);
        q += __shfl_xor(q, off);
    }
    __shared__ float rs[8];
    int wave = t >> 6, lane = t & 63;
    if (lane == 0) { rs[wave] = s; rs[4 + wave] = q; }
    __syncthreads();
    float st = rs[0] + rs[1] + rs[2] + rs[3];
    float qt = rs[4] + rs[5] + rs[6] + rs[7];
    float mu = st / (float)HW;
    float rstd = rsqrtf(qt / (float)HW - mu * mu + 1e-5f);
    for (int i = t; i < HWP; i += 256) {
        int py = i / HP, px = i % HP;
        float v = 0.f;
        if (py >= 1 && py <= H && px >= 1 && px <= H) {
            int j = (py - 1) * H + (px - 1);
            float u = (src[j] - mu) * rstd * g[j] + bv[j];
            v = u / (1.f + expf(-u));
        }
        dst[i] = v;
    }
}

// ---------------------------------------------------------------------------
// in-place spatial LN + affine + silu (layer 3; final conv handles bounds)
// ---------------------------------------------------------------------------
template<int HW>
__global__ void __launch_bounds__(256) k_ln_spatial(float* __restrict__ f,
                                                    const float* __restrict__ g,
                                                    const float* __restrict__ bv)
{
    size_t base = (size_t)blockIdx.x * HW;
    int t = threadIdx.x;
    float s = 0.f, q = 0.f;
    for (int i = t; i < HW; i += 256) {
        float v = f[base + i];
        s += v; q += v * v;
    }
    #pragma unroll
    for (int off = 32; off; off >>= 1) {
        s += __shfl_xor(s, off);
        q += __shfl_xor(q, off);
    }
    __shared__ float rs[8];
    int wave = t >> 6, lane = t & 63;
    if (lane == 0) { rs[wave] = s; rs[4 + wave] = q; }
    __syncthreads();
    float st = rs[0] + rs[1] + rs[2] + rs[3];
    float qt = rs[4] + rs[5] + rs[6] + rs[7];
    float mu = st / (float)HW;
    float rstd = rsqrtf(qt / (float)HW - mu * mu + 1e-5f);
    for (int i = t; i < HW; i += 256) {
        float v = (f[base + i] - mu) * rstd * g[i] + bv[i];
        f[base + i] = v / (1.f + expf(-v));
    }
}

// ---------------------------------------------------------------------------
// final convT 12->1, both-parity threads, compact input with boundary masks
// + silu + clip. grid = B*112*112/256 = 6272 blocks.
// ---------------------------------------------------------------------------
__global__ void __launch_bounds__(256) k_conv_final(const float* __restrict__ x,
                                                    const float* __restrict__ wr,
                                                    const float* __restrict__ bias,
                                                    float* __restrict__ out)
{
    constexpr int HIN = 112, CIN = 12, HP2 = 12544;
    int rem = blockIdx.x * 256 + threadIdx.x;
    int b   = rem / (HIN * HIN);
    int pix = rem % (HIN * HIN);
    int py = pix / HIN, px = pix % HIN;
    bool my0 = py >= 1, my2 = py + 1 < HIN;
    bool mx0 = px >= 1, mx2 = px + 1 < HIN;
    const float* xb = x + (size_t)b * CIN * HP2;
    const float4* w4 = (const float4*)wr;
    float a00 = 0.f, a01 = 0.f, a10 = 0.f, a11 = 0.f;
    #pragma unroll
    for (int ci = 0; ci < CIN; ++ci) {
        const float* xc = xb + ci * HP2 + py * HIN + px;
        float g00 = (my0 && mx0) ? xc[-HIN - 1] : 0.f;
        float g01 = my0 ? xc[-HIN] : 0.f;
        float g02 = (my0 && mx2) ? xc[-HIN + 1] : 0.f;
        float g10 = mx0 ? xc[-1] : 0.f;
        float g11 = xc[0];
        float g12 = mx2 ? xc[1] : 0.f;
        float g20 = (my2 && mx0) ? xc[HIN - 1] : 0.f;
        float g21 = my2 ? xc[HIN] : 0.f;
        float g22 = (my2 && mx2) ? xc[HIN + 1] : 0.f;
        float4 W0 = w4[ci];
        float4 W1 = w4[CIN + ci];
        float4 W2 = w4[2 * CIN + ci];
        float4 W3 = w4[3 * CIN + ci];
        a00 += g00 * W0.x + g01 * W0.y + g10 * W0.z + g11 * W0.w;
        a01 += g01 * W1.x + g02 * W1.y + g11 * W1.z + g12 * W1.w;
        a10 += g10 * W2.x + g11 * W2.y + g20 * W2.z + g21 * W2.w;
        a11 += g11 * W3.x + g12 * W3.y + g21 * W3.z + g22 * W3.w;
    }
    float bb = bias[0];
    float u00 = a00 + bb, u01 = a01 + bb, u10 = a10 + bb, u11 = a11 + bb;
    u00 = u00 / (1.f + expf(-u00));
    u01 = u01 / (1.f + expf(-u01));
    u10 = u10 / (1.f + expf(-u10));
    u11 = u11 / (1.f + expf(-u11));
    float2 v0, v1;
    v0.x = fminf(fmaxf(u00, 0.f), 1.f);
    v0.y = fminf(fmaxf(u01, 0.f), 1.f);
    v1.x = fminf(fmaxf(u10, 0.f), 1.f);
    v1.y = fminf(fmaxf(u11, 0.f), 1.f);
    float* orow = out + (size_t)b * 50176 + (2 * py) * 224 + 2 * px;
    *(float2*)orow = v0;
    *(float2*)(orow + 224) = v1;
}

// ---------------------------------------------------------------------------
// launch
// ---------------------------------------------------------------------------
extern "C" void kernel_launch(void* const* d_in, const int* in_sizes, int n_in,
                              void* d_out, int out_size, void* d_ws, size_t ws_size,
                              hipStream_t stream)
{
    const float* x       = (const float*)d_in[0];
    const float* ts      = (const float*)d_in[1];
    const float* Wp      = (const float*)d_in[2];
    const float* bp      = (const float*)d_in[3];
    const float* Wt1     = (const float*)d_in[4];
    const float* bt1     = (const float*)d_in[5];
    const float* Wt2     = (const float*)d_in[6];
    const float* bt2     = (const float*)d_in[7];
    const float* a0_g    = (const float*)d_in[8];
    const float* a0_b    = (const float*)d_in[9];
    const float* a0_Wqkv = (const float*)d_in[10];
    const float* a0_bqkv = (const float*)d_in[11];
    const float* a0_Wo   = (const float*)d_in[12];
    const float* a0_bo   = (const float*)d_in[13];
    const float* a1_g    = (const float*)d_in[14];
    const float* a1_b    = (const float*)d_in[15];
    const float* a1_Wqkv = (const float*)d_in[16];
    const float* a1_bqkv = (const float*)d_in[17];
    const float* a1_Wo   = (const float*)d_in[18];
    const float* a1_bo   = (const float*)d_in[19];
    const float* Wm0     = (const float*)d_in[20];
    const float* bm0     = (const float*)d_in[21];
    const float* Wm1     = (const float*)d_in[22];
    const float* bm1     = (const float*)d_in[23];
    const float* Wm2     = (const float*)d_in[24];
    const float* bm2     = (const float*)d_in[25];
    const float* Wd1     = (const float*)d_in[26];
    const float* bd1     = (const float*)d_in[27];
    const float* l1g     = (const float*)d_in[28];
    const float* l1b     = (const float*)d_in[29];
    const float* Wd2     = (const float*)d_in[30];
    const float* bd2     = (const float*)d_in[31];
    const float* l2g     = (const float*)d_in[32];
    const float* l2b     = (const float*)d_in[33];
    const float* Wd3     = (const float*)d_in[34];
    const float* bd3     = (const float*)d_in[35];
    const float* l3g     = (const float*)d_in[36];
    const float* l3b     = (const float*)d_in[37];
    const float* Wd4     = (const float*)d_in[38];
    const float* bd4     = (const float*)d_in[39];
    float* out = (float*)d_out;

    // arena (floats); R = 25088*96
    const size_t R = 2408448;
    float* ws   = (float*)d_ws;
    float* tvec = ws;                          // 96
    float* p0   = ws + 512;                    // R
    float* h    = ws + 512 + R;                // R
    float* qkvb = ws + 512 + 2 * R;            // 3R
    float* ob   = ws + 512 + 5 * R;            // R
    float* p1   = ws + 512 + 6 * R;            // R
    // attention K-split partials (aliases XP2/XP3 region, free during MHSA):
    float* part = ws + 512 + 7 * R;            // 45 MB
    // decoder aliases:
    float* XP1  = ws + 512 + 2 * R;            // (qkv region)
    float* C1   = ws + 512 + 5 * R;            // (ob+p1 regions)
    float* XP2  = ws + 512 + 7 * R;
    float* C2   = ws + 512;                    // (p0..qkv regions)
    float* XP3  = ws + 512 + 7 * R + 5529600;
    float* C3   = ws + 512;                    // (p0..XP2 regions)
    float* Wr   = ws + 512 + 7 * R + 5529600 + 10334208;  // 96,960
    const size_t NEED = (512 + 7 * R + 5529600 + 10334208 + 96960) * sizeof(float); // ~131.3 MB
    if (ws_size < NEED) return;

    k_time<<<1, 128, 0, stream>>>(ts, Wt1, bt1, Wt2, bt2, tvec);
    k_repack<<<379, 256, 0, stream>>>(Wd1, Wd2, Wd3, Wd4, Wr);
    k_patch<<<M_ROWS / 64, 256, 0, stream>>>(x, Wp, bp, p0);

    // MHSA block 0
    k_ln_row<<<1024, 256, 0, stream>>>(p0, a0_g, a0_b, h, M_ROWS);
    k_gemm96<3, false, false, false, false><<<M_ROWS / 64, 256, 0, stream>>>(
        h, a0_Wqkv, a0_bqkv, nullptr, nullptr, qkvb);
    k_attn_part<<<B_ * 4 * KS, 256, 0, stream>>>(qkvb, part);
    k_attn_comb<<<(B_ * 4 * NPATCH) / 256, 256, 0, stream>>>(part, ob);
    k_gemm96<1, false, true, false, false><<<M_ROWS / 64, 256, 0, stream>>>(
        ob, a0_Wo, a0_bo, p0, nullptr, p1);

    // MHSA block 1 (+time in epilogue)
    k_ln_row<<<1024, 256, 0, stream>>>(p1, a1_g, a1_b, h, M_ROWS);
    k_gemm96<3, false, false, false, false><<<M_ROWS / 64, 256, 0, stream>>>(
        h, a1_Wqkv, a1_bqkv, nullptr, nullptr, qkvb);
    k_attn_part<<<B_ * 4 * KS, 256, 0, stream>>>(qkvb, part);
    k_attn_comb<<<(B_ * 4 * NPATCH) / 256, 256, 0, stream>>>(part, ob);
    k_gemm96<1, false, true, true, false><<<M_ROWS / 64, 256, 0, stream>>>(
        ob, a1_Wo, a1_bo, p1, tvec, p0);

    // qkv region is now free: zero XP1 borders before MLP3 writes interior
    k_zb<<<3072, 256, 0, stream>>>(XP1);

    // MLP x3 (silu); last writes padded XP1[b][e][16][16]
    k_gemm96<1, true, false, false, false><<<M_ROWS / 64, 256, 0, stream>>>(
        p0, Wm0, bm0, nullptr, nullptr, p1);
    k_gemm96<1, true, false, false, false><<<M_ROWS / 64, 256, 0, stream>>>(
        p1, Wm1, bm1, nullptr, nullptr, p0);
    k_gemm96<1, true, false, false, true><<<M_ROWS / 64, 256, 0, stream>>>(
        p0, Wm2, bm2, nullptr, nullptr, XP1);

    // decoder (both-parity conv threads)
    k_convh<96, 14, 48, 8><<<6 * 98, 256, 0, stream>>>(XP1, Wr, bd1, C1);
    k_ln_pad<28><<<B_ * 48, 256, 0, stream>>>(C1, l1g, l1b, XP2);
    k_convh<48, 28, 24, 8><<<3 * 392, 256, 0, stream>>>(XP2, Wr + 73728, bd2, C2);
    k_ln_pad<56><<<B_ * 24, 256, 0, stream>>>(C2, l2g, l2b, XP3);
    k_convh<24, 56, 12, 12><<<1 * 1568, 256, 0, stream>>>(XP3, Wr + 92160, bd3, C3);
    k_ln_spatial<12544><<<B_ * 12, 256, 0, stream>>>(C3, l3g, l3b);
    k_conv_final<<<6272, 256, 0, stream>>>(C3, Wr + 96768, bd4, out);
}

// Round 7
// 765.139 us; speedup vs baseline: 1.4089x; 1.4089x over previous
//
#include <hip/hip_runtime.h>
#include <cmath>

// ---------------------------------------------------------------------------
// TimestepVisionTransformer — Round 6: revert convs to k_convg (r5-measured),
// convert transformer GEMMs to f16 MFMA (fp32 accumulate).
// B=128, IMG=224, P=16, C_IN=1, E=96, H=4, d=24, NAX=14, N=196, M=B*N=25088
// ---------------------------------------------------------------------------

#define B_   128
#define NPATCH 196
#define M_ROWS (B_*NPATCH)     // 25088
#define E_   96
#define KS   4
#define SEG  49

typedef _Float16 half8 __attribute__((ext_vector_type(8)));
typedef _Float16 half4v __attribute__((ext_vector_type(4)));
typedef float f32x4 __attribute__((ext_vector_type(4)));

// ---------------------------------------------------------------------------
// time embedding: 1 block x 128 threads
// ---------------------------------------------------------------------------
__global__ void k_time(const float* __restrict__ ts,
                       const float* __restrict__ Wt1, const float* __restrict__ bt1,
                       const float* __restrict__ Wt2, const float* __restrict__ bt2,
                       float* __restrict__ timev)
{
    __shared__ float h[128];
    float e = 0.69314718055994530942f * ts[0];
    float sv = sinf(e), cv = cosf(e);
    int t = threadIdx.x;
    float z = sv * Wt1[t] + cv * Wt1[128 + t] + bt1[t];
    h[t] = z / (1.f + expf(-z));
    __syncthreads();
    if (t < 96) {
        float acc = bt2[t];
        for (int j = 0; j < 128; ++j) acc += h[j] * Wt2[j * 96 + t];
        timev[t] = acc;
    }
}

// ---------------------------------------------------------------------------
// weight repack for all 4 convT layers into per-parity float4 taps.
// ---------------------------------------------------------------------------
__global__ void __launch_bounds__(256) k_repack(const float* __restrict__ w1,
                                                const float* __restrict__ w2,
                                                const float* __restrict__ w3,
                                                const float* __restrict__ w4f,
                                                float* __restrict__ wr)
{
    int i = blockIdx.x * 256 + threadIdx.x;
    const float* src; int CIN, COUT, e; float* dst;
    if      (i < 73728) { src = w1;  CIN = 96; COUT = 48; e = i;          dst = wr; }
    else if (i < 92160) { src = w2;  CIN = 48; COUT = 24; e = i - 73728;  dst = wr + 73728; }
    else if (i < 96768) { src = w3;  CIN = 24; COUT = 12; e = i - 92160;  dst = wr + 92160; }
    else if (i < 96960) { src = w4f; CIN = 12; COUT = 1;  e = i - 96768;  dst = wr + 96768; }
    else return;
    int per = CIN * COUT * 4;
    int par = e / per, rem = e % per;
    int ci = rem / (COUT * 4);
    int o  = (rem >> 2) % COUT;
    int j  = rem & 3;
    int ry = par >> 1, rx = par & 1;
    int wy = (j < 2)  ? (3 - ry) : (1 - ry);
    int wx = (j & 1)  ? (1 - rx) : (3 - rx);
    dst[e] = src[(ci * COUT + o) * 16 + wy * 4 + wx];
}

// ---------------------------------------------------------------------------
// transformer weight convert+transpose to half: Wt[n][k] = W[k][n]
// segments (halves): qkv0 27648, qkv1 27648, wo0 9216, wo1 9216,
//                    wm0 9216, wm1 9216, wm2 9216  (total 101376)
// ---------------------------------------------------------------------------
__global__ void __launch_bounds__(256) k_wcvt(const float* __restrict__ qkv0,
                                              const float* __restrict__ qkv1,
                                              const float* __restrict__ wo0,
                                              const float* __restrict__ wo1,
                                              const float* __restrict__ wm0,
                                              const float* __restrict__ wm1,
                                              const float* __restrict__ wm2,
                                              _Float16* __restrict__ wh)
{
    int i = blockIdx.x * 256 + threadIdx.x;
    const float* src; int N; int e;
    if      (i < 27648)  { src = qkv0; N = 288; e = i; }
    else if (i < 55296)  { src = qkv1; N = 288; e = i - 27648; }
    else if (i < 64512)  { src = wo0;  N = 96;  e = i - 55296; }
    else if (i < 73728)  { src = wo1;  N = 96;  e = i - 64512; }
    else if (i < 82944)  { src = wm0;  N = 96;  e = i - 73728; }
    else if (i < 92160)  { src = wm1;  N = 96;  e = i - 82944; }
    else if (i < 101376) { src = wm2;  N = 96;  e = i - 92160; }
    else return;
    int n = e / 96, k = e % 96;
    wh[i] = (_Float16)src[k * N + n];
}

// ---------------------------------------------------------------------------
// zero the borders of XP1 [128*96 planes][16][16] (interior written by MLP3)
// ---------------------------------------------------------------------------
__global__ void __launch_bounds__(256) k_zb(float* __restrict__ xp)
{
    int idx = blockIdx.x * 256 + threadIdx.x;   // plane*64 + j
    int plane = idx >> 6, j = idx & 63;
    if (plane >= 12288 || j >= 60) return;
    int py, px;
    if      (j < 16) { py = 0;      px = j; }
    else if (j < 32) { py = 15;     px = j - 16; }
    else if (j < 46) { py = j - 31; px = 0; }
    else             { py = j - 45; px = 15; }
    xp[(size_t)plane * 256 + py * 16 + px] = 0.f;
}

// ---------------------------------------------------------------------------
// patch embed GEMM  [25088 x 256] @ WpT[256 x 96]  + bias + RoPE (fp32)
// ---------------------------------------------------------------------------
__global__ void __launch_bounds__(256) k_patch(const float* __restrict__ x,
                                               const float* __restrict__ Wp,
                                               const float* __restrict__ bp,
                                               float* __restrict__ out)
{
    __shared__ float As[64][65];
    __shared__ float Ws[64][97];
    int t = threadIdx.x;
    int p0 = blockIdx.x * 64;
    int rg = t >> 4, cg = t & 15;
    float acc[4][6] = {};

    for (int kc = 0; kc < 4; ++kc) {
        __syncthreads();
        for (int idx = t; idx < 64 * 64; idx += 256) {
            int p = idx >> 6, kl = idx & 63;
            int patch = p0 + p;
            int b = patch / NPATCH, n = patch % NPATCH;
            int ny = n / 14, nx = n % 14;
            int py = kc * 4 + (kl >> 4), px = kl & 15;
            As[p][kl] = x[((size_t)b * 224 + ny * 16 + py) * 224 + nx * 16 + px];
        }
        for (int idx = t; idx < 64 * 96; idx += 256) {
            int e = idx >> 6, kl = idx & 63;
            Ws[kl][e] = Wp[e * 256 + kc * 64 + kl];
        }
        __syncthreads();
        for (int kk = 0; kk < 64; ++kk) {
            float a0 = As[rg * 4 + 0][kk];
            float a1 = As[rg * 4 + 1][kk];
            float a2 = As[rg * 4 + 2][kk];
            float a3 = As[rg * 4 + 3][kk];
            const float* wrow = &Ws[kk][cg * 6];
            #pragma unroll
            for (int j = 0; j < 6; ++j) {
                float wv = wrow[j];
                acc[0][j] += a0 * wv; acc[1][j] += a1 * wv;
                acc[2][j] += a2 * wv; acc[3][j] += a3 * wv;
            }
        }
    }
    #pragma unroll
    for (int i = 0; i < 4; ++i) {
        int patch = p0 + rg * 4 + i;
        int n = patch % NPATCH;
        int ny = n / 14, nx = n % 14;
        float yx = (float)(ny + nx);
        #pragma unroll
        for (int j = 0; j < 3; ++j) {
            int e0 = cg * 6 + 2 * j;
            float xe = acc[i][2 * j]     + bp[e0];
            float ye = acc[i][2 * j + 1] + bp[e0 + 1];
            float fi = (float)(e0 >> 1);
            float theta = expf(fi * (-2.f / 96.f) * 9.210340371976184f);
            float ang = theta * yx;
            float c = cosf(ang), s = sinf(ang);
            out[(size_t)patch * 96 + e0]     = xe * c - ye * s;
            out[(size_t)patch * 96 + e0 + 1] = xe * s + ye * c;
        }
    }
}

// ---------------------------------------------------------------------------
// row LayerNorm over 96, wave per row
// ---------------------------------------------------------------------------
__global__ void __launch_bounds__(256) k_ln_row(const float* __restrict__ x,
                                                const float* __restrict__ g,
                                                const float* __restrict__ bv,
                                                float* __restrict__ out, int M)
{
    int lane = threadIdx.x & 63;
    int gw = (blockIdx.x * 256 + threadIdx.x) >> 6;
    int nw = (gridDim.x * 256) >> 6;
    float g0 = g[lane], b0 = bv[lane];
    float g1 = 0.f, b1 = 0.f;
    if (lane < 32) { g1 = g[64 + lane]; b1 = bv[64 + lane]; }
    for (int r = gw; r < M; r += nw) {
        const float* xr = x + (size_t)r * 96;
        float a = xr[lane];
        float c = (lane < 32) ? xr[64 + lane] : 0.f;
        float s = a + c, q = a * a + c * c;
        #pragma unroll
        for (int off = 32; off; off >>= 1) {
            s += __shfl_xor(s, off);
            q += __shfl_xor(q, off);
        }
        float mu = s * (1.f / 96.f);
        float rstd = rsqrtf(q * (1.f / 96.f) - mu * mu + 1e-5f);
        float* orow = out + (size_t)r * 96;
        orow[lane] = (a - mu) * rstd * g0 + b0;
        if (lane < 32) orow[64 + lane] = (c - mu) * rstd * g1 + b1;
    }
}

// ---------------------------------------------------------------------------
// MFMA row GEMM: A[M,96] (fp32 in) @ W[96, NCHUNKS*96] (pre-transposed half
// Wt[n][k]) + bias, epilogues. 64 rows/block, 256 threads (4 waves).
// Wave w: rows w*16..w*16+15, six 16x16 col-tiles per chunk, K=96=3 steps.
// Frag layouts (guide §3, HW-verified): A m=lane&15,k=quad*8+j;
// B n=lane&15,k=quad*8+j; D col=lane&15,row=quad*4+reg.
// ---------------------------------------------------------------------------
template<int NCHUNKS, bool SILU, bool RES, bool ADDTIME, bool PADW>
__global__ void __launch_bounds__(256) k_gemm_mfma(const float* __restrict__ A,
                                                   const _Float16* __restrict__ Wt,
                                                   const float* __restrict__ bias,
                                                   const float* __restrict__ res,
                                                   const float* __restrict__ timev,
                                                   float* __restrict__ out)
{
    __shared__ __align__(16) _Float16 Ah[64 * 96];
    __shared__ __align__(16) _Float16 Wh[96 * 96];
    constexpr int NTOT = NCHUNKS * 96;
    int t = threadIdx.x;
    size_t row0 = (size_t)blockIdx.x * 64;

    // stage A -> half (vectorized: 1536 float4 = 6144 floats)
    const float4* a4 = (const float4*)(A + row0 * 96);
    for (int i = t; i < 1536; i += 256) {
        float4 v = a4[i];
        half4v hv;
        hv[0] = (_Float16)v.x; hv[1] = (_Float16)v.y;
        hv[2] = (_Float16)v.z; hv[3] = (_Float16)v.w;
        *(half4v*)&Ah[i * 4] = hv;
    }

    int wave = t >> 6, lane = t & 63;
    int lm = lane & 15, quad = lane >> 4;
    const f32x4 vzero = {0.f, 0.f, 0.f, 0.f};

    for (int ch = 0; ch < NCHUNKS; ++ch) {
        __syncthreads();   // protect Wh reuse (and cover Ah at ch=0)
        {
            const uint4* src = (const uint4*)(Wt + (size_t)ch * 9216);
            uint4* dst = (uint4*)Wh;
            for (int i = t; i < 1152; i += 256) dst[i] = src[i];
        }
        __syncthreads();

        // a-frags for this wave's 16-row stripe (reused across col-tiles)
        half8 af[3];
        #pragma unroll
        for (int ks = 0; ks < 3; ++ks)
            af[ks] = *(const half8*)&Ah[(wave * 16 + lm) * 96 + ks * 32 + quad * 8];

        f32x4 acc[6];
        #pragma unroll
        for (int ct = 0; ct < 6; ++ct) acc[ct] = vzero;

        #pragma unroll
        for (int ct = 0; ct < 6; ++ct) {
            #pragma unroll
            for (int ks = 0; ks < 3; ++ks) {
                half8 bf = *(const half8*)&Wh[(ct * 16 + lm) * 96 + ks * 32 + quad * 8];
                acc[ct] = __builtin_amdgcn_mfma_f32_16x16x32_f16(af[ks], bf, acc[ct], 0, 0, 0);
            }
        }

        // epilogue
        #pragma unroll
        for (int ct = 0; ct < 6; ++ct) {
            #pragma unroll
            for (int r = 0; r < 4; ++r) {
                int lr = wave * 16 + quad * 4 + r;
                size_t row = row0 + lr;
                int lc = ct * 16 + lm;
                int col = ch * 96 + lc;
                float v = acc[ct][r] + bias[col];
                if constexpr (RES)     v += res[row * 96 + lc];
                if constexpr (ADDTIME) v += timev[lc];
                if constexpr (SILU)    v = v / (1.f + expf(-v));
                if constexpr (PADW) {
                    size_t b = row / NPATCH; int n = (int)(row % NPATCH);
                    int ny = n / 14, nx = n % 14;
                    out[(b * 96 + col) * 256 + (1 + ny) * 16 + (1 + nx)] = v;
                } else {
                    out[row * NTOT + col] = v;
                }
            }
        }
    }
}

// ---------------------------------------------------------------------------
// attention partials: block = (b,h,seg). Stage 49 K/V rows in LDS; one
// thread = one query; uniform-address ds_read -> broadcast.
// ---------------------------------------------------------------------------
__global__ void __launch_bounds__(256) k_attn_part(const float* __restrict__ qkv,
                                                   float* __restrict__ part)
{
    int blk = blockIdx.x;          // bh*KS + seg
    int seg = blk % KS;
    int bh  = blk / KS;
    int b = bh >> 2, h = bh & 3;
    const float* base = qkv + (size_t)b * NPATCH * 288 + h * 24;
    __shared__ __align__(16) float KV[SEG * 48];
    int t = threadIdx.x;
    int k0 = seg * SEG;
    for (int i = t; i < SEG * 48; i += 256) {
        int k = i / 48, j = i % 48;
        KV[i] = base[(size_t)(k0 + k) * 288 + 96 + (j < 24 ? j : j + 72)];
    }
    __syncthreads();

    int q = (t < NPATCH) ? t : 0;
    float qv[24], acc[24];
    const float4* qrow = (const float4*)(base + (size_t)q * 288);
    #pragma unroll
    for (int j = 0; j < 6; ++j) {
        float4 v = qrow[j];
        qv[4 * j] = v.x; qv[4 * j + 1] = v.y; qv[4 * j + 2] = v.z; qv[4 * j + 3] = v.w;
    }
    #pragma unroll
    for (int d = 0; d < 24; ++d) acc[d] = 0.f;
    float sum = 0.f;
    const float scale = 0.2041241452319315f;   // 1/sqrt(24)

    #pragma unroll 2
    for (int k = 0; k < SEG; ++k) {
        const float4* kr = (const float4*)(&KV[k * 48]);   // uniform addr
        float s0 = 0.f, s1 = 0.f, s2 = 0.f, s3 = 0.f;
        #pragma unroll
        for (int j = 0; j < 6; ++j) {
            float4 Kv = kr[j];
            s0 += qv[4 * j]     * Kv.x;
            s1 += qv[4 * j + 1] * Kv.y;
            s2 += qv[4 * j + 2] * Kv.z;
            s3 += qv[4 * j + 3] * Kv.w;
        }
        float s = (s0 + s1) + (s2 + s3);
        float p = __expf(fminf(s * scale, 60.f));
        sum += p;
        #pragma unroll
        for (int j = 0; j < 6; ++j) {
            float4 Vv = kr[6 + j];
            acc[4 * j]     += p * Vv.x;
            acc[4 * j + 1] += p * Vv.y;
            acc[4 * j + 2] += p * Vv.z;
            acc[4 * j + 3] += p * Vv.w;
        }
    }

    if (t < NPATCH) {
        float4* pp = (float4*)(part + ((size_t)blk * NPATCH + t) * 28);
        #pragma unroll
        for (int j = 0; j < 6; ++j) {
            float4 v;
            v.x = acc[4 * j]; v.y = acc[4 * j + 1];
            v.z = acc[4 * j + 2]; v.w = acc[4 * j + 3];
            pp[j] = v;
        }
        float4 sv; sv.x = sum; sv.y = 0.f; sv.z = 0.f; sv.w = 0.f;
        pp[6] = sv;
    }
}

// ---------------------------------------------------------------------------
// combine K-split partials: o[b][q][h*24..] = Σacc / Σsum
// ---------------------------------------------------------------------------
__global__ void __launch_bounds__(256) k_attn_comb(const float* __restrict__ part,
                                                   float* __restrict__ o)
{
    int idx = blockIdx.x * 256 + threadIdx.x;   // bh*196 + q
    int bh = idx / NPATCH, q = idx % NPATCH;
    int b = bh >> 2, h = bh & 3;
    float acc[24];
    #pragma unroll
    for (int d = 0; d < 24; ++d) acc[d] = 0.f;
    float sum = 0.f;
    #pragma unroll
    for (int s = 0; s < KS; ++s) {
        const float4* pp = (const float4*)(part + ((size_t)(bh * KS + s) * NPATCH + q) * 28);
        #pragma unroll
        for (int j = 0; j < 6; ++j) {
            float4 v = pp[j];
            acc[4 * j]     += v.x;
            acc[4 * j + 1] += v.y;
            acc[4 * j + 2] += v.z;
            acc[4 * j + 3] += v.w;
        }
        sum += pp[6].x;
    }
    float inv = 1.f / sum;
    float4* orow = (float4*)(o + ((size_t)b * NPATCH + q) * 96 + h * 24);
    #pragma unroll
    for (int j = 0; j < 6; ++j) {
        float4 v;
        v.x = acc[4 * j] * inv; v.y = acc[4 * j + 1] * inv;
        v.z = acc[4 * j + 2] * inv; v.w = acc[4 * j + 3] * inv;
        orow[j] = v;
    }
}

// ---------------------------------------------------------------------------
// transposed conv on zero-padded input XP[b][CIN][HIN+2][HIN+2].
// Channel-group split (r5-measured config). Weights via s_load broadcast.
// grid = 2 * (COUT/G) * B*HIN*HIN/256.
// ---------------------------------------------------------------------------
template<int CIN, int HIN, int COUT, int G>
__global__ void __launch_bounds__(256) k_convg(const float* __restrict__ xp,
                                               const float* __restrict__ wr,
                                               const float* __restrict__ bias,
                                               float* __restrict__ out)
{
    constexpr int HP = HIN + 2;
    constexpr int HO = 2 * HIN;
    constexpr int NPB = (B_ * HIN * HIN) / 256;   // pixel-blocks per (ry,og)
    int pb = blockIdx.x % NPB;
    int z  = blockIdx.x / NPB;        // z = ry * (COUT/G) + og
    int og = z % (COUT / G);
    int ry = z / (COUT / G);
    int o0 = og * G;
    int rem = pb * 256 + threadIdx.x; // in [0, B*HIN*HIN)
    int b   = rem / (HIN * HIN);
    int pix = rem % (HIN * HIN);
    int py = pix / HIN, px = pix % HIN;
    const float* xb = xp + ((size_t)b * CIN) * (HP * HP) + (py + ry) * HP + px;
    const float4* w4 = (const float4*)wr;
    float acc0[G], acc1[G];
    #pragma unroll
    for (int o = 0; o < G; ++o) { acc0[o] = 0.f; acc1[o] = 0.f; }
    float f00 = xb[0], f01 = xb[1], f02 = xb[2];
    float f10 = xb[HP], f11 = xb[HP + 1], f12 = xb[HP + 2];
    for (int ci = 0; ci < CIN; ++ci) {
        int cn = (ci + 1 < CIN) ? (ci + 1) : (CIN - 1);
        const float* xn = xb + (size_t)cn * (HP * HP);
        float n00 = xn[0], n01 = xn[1], n02 = xn[2];
        float n10 = xn[HP], n11 = xn[HP + 1], n12 = xn[HP + 2];
        const float4* w0 = w4 + ((size_t)(2 * ry) * CIN + ci) * COUT + o0;
        const float4* w1 = w0 + (size_t)CIN * COUT;
        #pragma unroll
        for (int o = 0; o < G; ++o) {
            float4 W0 = w0[o], W1 = w1[o];
            acc0[o] += f00 * W0.x + f01 * W0.y + f10 * W0.z + f11 * W0.w;
            acc1[o] += f01 * W1.x + f02 * W1.y + f11 * W1.z + f12 * W1.w;
        }
        f00 = n00; f01 = n01; f02 = n02; f10 = n10; f11 = n11; f12 = n12;
    }
    int oy = 2 * py + ry;
    #pragma unroll
    for (int o = 0; o < G; ++o) {
        float bb = bias[o0 + o];
        float2 v; v.x = acc0[o] + bb; v.y = acc1[o] + bb;
        *(float2*)(out + ((size_t)(b * COUT + o0 + o) * HO + oy) * HO + 2 * px) = v;
    }
}

// ---------------------------------------------------------------------------
// spatial LN (per b,o over H*H) + per-position affine + silu, writing into
// zero-padded layout XP[plane][(H+2)][(H+2)] for the next conv.
// ---------------------------------------------------------------------------
template<int H>
__global__ void __launch_bounds__(256) k_ln_pad(const float* __restrict__ cin,
                                                const float* __restrict__ g,
                                                const float* __restrict__ bv,
                                                float* __restrict__ xp)
{
    constexpr int HW = H * H;
    constexpr int HP = H + 2;
    constexpr int HWP = HP * HP;
    size_t plane = blockIdx.x;
    const float* src = cin + plane * HW;
    float* dst = xp + plane * HWP;
    int t = threadIdx.x;
    float s = 0.f, q = 0.f;
    for (int i = t; i < HW; i += 256) {
        float v = src[i];
        s += v; q += v * v;
    }
    #pragma unroll
    for (int off = 32; off; off >>= 1) {
        s += __shfl_xor(s, off);
        q += __shfl_xor(q, off);
    }
    __shared__ float rs[8];
    int wave = t >> 6, lane = t & 63;
    if (lane == 0) { rs[wave] = s; rs[4 + wave] = q; }
    __syncthreads();
    float st = rs[0] + rs[1] + rs[2] + rs[3];
    float qt = rs[4] + rs[5] + rs[6] + rs[7];
    float mu = st / (float)HW;
    float rstd = rsqrtf(qt / (float)HW - mu * mu + 1e-5f);
    for (int i = t; i < HWP; i += 256) {
        int py = i / HP, px = i % HP;
        float v = 0.f;
        if (py >= 1 && py <= H && px >= 1 && px <= H) {
            int j = (py - 1) * H + (px - 1);
            float u = (src[j] - mu) * rstd * g[j] + bv[j];
            v = u / (1.f + expf(-u));
        }
        dst[i] = v;
    }
}

// ---------------------------------------------------------------------------
// in-place spatial LN + affine + silu (layer 3; final conv handles bounds)
// ---------------------------------------------------------------------------
template<int HW>
__global__ void __launch_bounds__(256) k_ln_spatial(float* __restrict__ f,
                                                    const float* __restrict__ g,
                                                    const float* __restrict__ bv)
{
    size_t base = (size_t)blockIdx.x * HW;
    int t = threadIdx.x;
    float s = 0.f, q = 0.f;
    for (int i = t; i < HW; i += 256) {
        float v = f[base + i];
        s += v; q += v * v;
    }
    #pragma unroll
    for (int off = 32; off; off >>= 1) {
        s += __shfl_xor(s, off);
        q += __shfl_xor(q, off);
    }
    __shared__ float rs[8];
    int wave = t >> 6, lane = t & 63;
    if (lane == 0) { rs[wave] = s; rs[4 + wave] = q; }
    __syncthreads();
    float st = rs[0] + rs[1] + rs[2] + rs[3];
    float qt = rs[4] + rs[5] + rs[6] + rs[7];
    float mu = st / (float)HW;
    float rstd = rsqrtf(qt / (float)HW - mu * mu + 1e-5f);
    for (int i = t; i < HW; i += 256) {
        float v = (f[base + i] - mu) * rstd * g[i] + bv[i];
        f[base + i] = v / (1.f + expf(-v));
    }
}

// ---------------------------------------------------------------------------
// final convT 12->1 on compact input with boundary masks + silu + clip
// (r4-measured 2-parity version)
// ---------------------------------------------------------------------------
__global__ void __launch_bounds__(256) k_conv_final(const float* __restrict__ x,
                                                    const float* __restrict__ wr,
                                                    const float* __restrict__ bias,
                                                    float* __restrict__ out)
{
    constexpr int HIN = 112, CIN = 12, HP2 = 12544;
    constexpr int NPB = (B_ * HIN * HIN) / 256;   // 6272
    int pb = blockIdx.x % NPB;
    int ry = blockIdx.x / NPB;
    int rem = pb * 256 + threadIdx.x;
    int b   = rem / (HIN * HIN);
    int pix = rem % (HIN * HIN);
    int py = pix / HIN, px = pix % HIN;
    int r0 = py + ry - 1, r1 = r0 + 1;
    bool my0 = r0 >= 0, my1 = r1 < HIN;
    bool mx0 = px >= 1, mx2 = px + 1 < HIN;
    const float* xb = x + (size_t)b * CIN * HP2;
    const float4* w4 = (const float4*)wr;
    float acc0 = 0.f, acc1 = 0.f;
    #pragma unroll
    for (int ci = 0; ci < CIN; ++ci) {
        const float* xc = xb + ci * HP2;
        const float* xr0 = xc + r0 * HIN + px;
        const float* xr1 = xc + r1 * HIN + px;
        float g00 = (my0 && mx0) ? xr0[-1] : 0.f;
        float g01 = my0 ? xr0[0] : 0.f;
        float g02 = (my0 && mx2) ? xr0[1] : 0.f;
        float g10 = (my1 && mx0) ? xr1[-1] : 0.f;
        float g11 = my1 ? xr1[0] : 0.f;
        float g12 = (my1 && mx2) ? xr1[1] : 0.f;
        float4 W0 = w4[(2 * ry) * CIN + ci];
        float4 W1 = w4[(2 * ry + 1) * CIN + ci];
        acc0 += g00 * W0.x + g01 * W0.y + g10 * W0.z + g11 * W0.w;
        acc1 += g01 * W1.x + g02 * W1.y + g11 * W1.z + g12 * W1.w;
    }
    float bb = bias[0];
    float u0 = acc0 + bb, u1 = acc1 + bb;
    u0 = u0 / (1.f + expf(-u0));
    u1 = u1 / (1.f + expf(-u1));
    float2 v;
    v.x = fminf(fmaxf(u0, 0.f), 1.f);
    v.y = fminf(fmaxf(u1, 0.f), 1.f);
    int oy = 2 * py + ry;
    *(float2*)(out + (size_t)b * 50176 + oy * 224 + 2 * px) = v;
}

// ---------------------------------------------------------------------------
// launch
// ---------------------------------------------------------------------------
extern "C" void kernel_launch(void* const* d_in, const int* in_sizes, int n_in,
                              void* d_out, int out_size, void* d_ws, size_t ws_size,
                              hipStream_t stream)
{
    const float* x       = (const float*)d_in[0];
    const float* ts      = (const float*)d_in[1];
    const float* Wp      = (const float*)d_in[2];
    const float* bp      = (const float*)d_in[3];
    const float* Wt1     = (const float*)d_in[4];
    const float* bt1     = (const float*)d_in[5];
    const float* Wt2     = (const float*)d_in[6];
    const float* bt2     = (const float*)d_in[7];
    const float* a0_g    = (const float*)d_in[8];
    const float* a0_b    = (const float*)d_in[9];
    const float* a0_Wqkv = (const float*)d_in[10];
    const float* a0_bqkv = (const float*)d_in[11];
    const float* a0_Wo   = (const float*)d_in[12];
    const float* a0_bo   = (const float*)d_in[13];
    const float* a1_g    = (const float*)d_in[14];
    const float* a1_b    = (const float*)d_in[15];
    const float* a1_Wqkv = (const float*)d_in[16];
    const float* a1_bqkv = (const float*)d_in[17];
    const float* a1_Wo   = (const float*)d_in[18];
    const float* a1_bo   = (const float*)d_in[19];
    const float* Wm0     = (const float*)d_in[20];
    const float* bm0     = (const float*)d_in[21];
    const float* Wm1     = (const float*)d_in[22];
    const float* bm1     = (const float*)d_in[23];
    const float* Wm2     = (const float*)d_in[24];
    const float* bm2     = (const float*)d_in[25];
    const float* Wd1     = (const float*)d_in[26];
    const float* bd1     = (const float*)d_in[27];
    const float* l1g     = (const float*)d_in[28];
    const float* l1b     = (const float*)d_in[29];
    const float* Wd2     = (const float*)d_in[30];
    const float* bd2     = (const float*)d_in[31];
    const float* l2g     = (const float*)d_in[32];
    const float* l2b     = (const float*)d_in[33];
    const float* Wd3     = (const float*)d_in[34];
    const float* bd3     = (const float*)d_in[35];
    const float* l3g     = (const float*)d_in[36];
    const float* l3b     = (const float*)d_in[37];
    const float* Wd4     = (const float*)d_in[38];
    const float* bd4     = (const float*)d_in[39];
    float* out = (float*)d_out;

    // arena (floats); R = 25088*96
    const size_t R = 2408448;
    float* ws   = (float*)d_ws;
    float* tvec = ws;                          // 96
    float* p0   = ws + 512;                    // R
    float* h    = ws + 512 + R;                // R
    float* qkvb = ws + 512 + 2 * R;            // 3R
    float* ob   = ws + 512 + 5 * R;            // R
    float* p1   = ws + 512 + 6 * R;            // R
    // attention K-split partials (aliases decoder region, free during MHSA):
    float* part = ws + 512 + 7 * R;            // 45 MB
    // decoder aliases:
    float* XP1  = ws + 512 + 2 * R;            // (qkv region)
    float* C1   = ws + 512 + 5 * R;            // (ob+p1 regions)
    float* XP2  = ws + 512 + 7 * R;
    float* C2   = ws + 512;                    // (p0..qkv regions)
    float* XP3  = ws + 512 + 7 * R + 5529600;
    float* C3   = ws + 512;                    // (p0..XP2 regions)
    float* Wr   = ws + 512 + 7 * R + 5529600 + 10334208;  // 96,960 floats
    _Float16* WH = (_Float16*)(Wr + 96960);                // 101,376 halves
    const size_t NEED = (512 + 7 * R + 5529600 + 10334208 + 96960 + 50688 + 16)
                        * sizeof(float);                   // ~131.5 MB
    if (ws_size < NEED) return;

    // half-weight segment offsets
    _Float16* WHqkv0 = WH;
    _Float16* WHqkv1 = WH + 27648;
    _Float16* WHwo0  = WH + 55296;
    _Float16* WHwo1  = WH + 64512;
    _Float16* WHwm0  = WH + 73728;
    _Float16* WHwm1  = WH + 82944;
    _Float16* WHwm2  = WH + 92160;

    k_time<<<1, 128, 0, stream>>>(ts, Wt1, bt1, Wt2, bt2, tvec);
    k_repack<<<379, 256, 0, stream>>>(Wd1, Wd2, Wd3, Wd4, Wr);
    k_wcvt<<<396, 256, 0, stream>>>(a0_Wqkv, a1_Wqkv, a0_Wo, a1_Wo,
                                    Wm0, Wm1, Wm2, WH);
    k_patch<<<M_ROWS / 64, 256, 0, stream>>>(x, Wp, bp, p0);

    // MHSA block 0
    k_ln_row<<<1024, 256, 0, stream>>>(p0, a0_g, a0_b, h, M_ROWS);
    k_gemm_mfma<3, false, false, false, false><<<M_ROWS / 64, 256, 0, stream>>>(
        h, WHqkv0, a0_bqkv, nullptr, nullptr, qkvb);
    k_attn_part<<<B_ * 4 * KS, 256, 0, stream>>>(qkvb, part);
    k_attn_comb<<<(B_ * 4 * NPATCH) / 256, 256, 0, stream>>>(part, ob);
    k_gemm_mfma<1, false, true, false, false><<<M_ROWS / 64, 256, 0, stream>>>(
        ob, WHwo0, a0_bo, p0, nullptr, p1);

    // MHSA block 1 (+time in epilogue)
    k_ln_row<<<1024, 256, 0, stream>>>(p1, a1_g, a1_b, h, M_ROWS);
    k_gemm_mfma<3, false, false, false, false><<<M_ROWS / 64, 256, 0, stream>>>(
        h, WHqkv1, a1_bqkv, nullptr, nullptr, qkvb);
    k_attn_part<<<B_ * 4 * KS, 256, 0, stream>>>(qkvb, part);
    k_attn_comb<<<(B_ * 4 * NPATCH) / 256, 256, 0, stream>>>(part, ob);
    k_gemm_mfma<1, false, true, true, false><<<M_ROWS / 64, 256, 0, stream>>>(
        ob, WHwo1, a1_bo, p1, tvec, p0);

    // qkv region is now free: zero XP1 borders before MLP3 writes interior
    k_zb<<<3072, 256, 0, stream>>>(XP1);

    // MLP x3 (silu); last writes padded XP1[b][e][16][16]
    k_gemm_mfma<1, true, false, false, false><<<M_ROWS / 64, 256, 0, stream>>>(
        p0, WHwm0, bm0, nullptr, nullptr, p1);
    k_gemm_mfma<1, true, false, false, false><<<M_ROWS / 64, 256, 0, stream>>>(
        p1, WHwm1, bm1, nullptr, nullptr, p0);
    k_gemm_mfma<1, true, false, false, true><<<M_ROWS / 64, 256, 0, stream>>>(
        p0, WHwm2, bm2, nullptr, nullptr, XP1);

    // decoder (r5-measured channel-group split convs)
    k_convg<96, 14, 48, 8><<<2 * 6 * 98, 256, 0, stream>>>(XP1, Wr, bd1, C1);
    k_ln_pad<28><<<B_ * 48, 256, 0, stream>>>(C1, l1g, l1b, XP2);
    k_convg<48, 28, 24, 8><<<2 * 3 * 392, 256, 0, stream>>>(XP2, Wr + 73728, bd2, C2);
    k_ln_pad<56><<<B_ * 24, 256, 0, stream>>>(C2, l2g, l2b, XP3);
    k_convg<24, 56, 12, 12><<<2 * 1 * 1568, 256, 0, stream>>>(XP3, Wr + 92160, bd3, C3);
    k_ln_spatial<12544><<<B_ * 12, 256, 0, stream>>>(C3, l3g, l3b);
    k_conv_final<<<2 * 6272, 256, 0, stream>>>(C3, Wr + 96768, bd4, out);
}